// Round 4
// baseline (597.335 us; speedup 1.0000x reference)
//
#include <hip/hip_runtime.h>
#include <hip/hip_bf16.h>

typedef __attribute__((ext_vector_type(8))) short short8;
typedef __attribute__((ext_vector_type(4))) float f32x4;

#define BT 65536      // B*T rows
#define D  512
#define NB 1024       // batches
#define NH 768        // 3*256 hidden

static __device__ __forceinline__ unsigned short f2bf(float f) {
    union { __hip_bfloat16 h; unsigned short u; } cv;
    cv.h = __float2bfloat16(f);
    return cv.u;
}

static __device__ __forceinline__ float gelu(float x) {
    return 0.5f * x * (1.0f + erff(x * 0.70710678118654752f));
}

// byte offset into an LDS tile laid out [rows][64 bf16] with XOR swizzle on 16B chunks
static __device__ __forceinline__ int swz(int row, int ch) {
    return row * 128 + (((ch ^ (row & 7)) & 7) << 4);
}

static __device__ __forceinline__ short8 pack8(const float4& v0, const float4& v1) {
    short8 r;
    r[0] = (short)f2bf(v0.x); r[1] = (short)f2bf(v0.y);
    r[2] = (short)f2bf(v0.z); r[3] = (short)f2bf(v0.w);
    r[4] = (short)f2bf(v1.x); r[5] = (short)f2bf(v1.y);
    r[6] = (short)f2bf(v1.z); r[7] = (short)f2bf(v1.w);
    return r;
}

// ---------------- transpose [R][C] f32 -> out[c][r] bf16 (row stride ostride) ----------------
__global__ void transpose_to_bf16(const float* __restrict__ in, unsigned short* __restrict__ out,
                                  int R, int C, int ostride) {
    __shared__ float tile[32][33];
    int r0 = blockIdx.x * 32, c0 = blockIdx.y * 32;
    int tx = threadIdx.x, ty = threadIdx.y; // 32 x 8
    for (int yy = 0; yy < 32; yy += 8)
        tile[ty + yy][tx] = in[(size_t)(r0 + ty + yy) * C + c0 + tx];
    __syncthreads();
    for (int yy = 0; yy < 32; yy += 8)
        out[(size_t)(c0 + ty + yy) * ostride + r0 + tx] = f2bf(tile[tx][ty + yy]);
}

// ---------------- concat small scorer params ----------------
__global__ void prep_cat(const float* b1_0, const float* b1_1, const float* b1_2,
                         const float* W2_0, const float* W2_1, const float* W2_2,
                         const float* b2_0, const float* b2_1, const float* b2_2,
                         float* b1cat, float* W2cat, float* b2cat) {
    int t = threadIdx.x;            // 768 threads
    int s = t >> 8, j = t & 255;
    const float* b1p = (s == 0) ? b1_0 : (s == 1) ? b1_1 : b1_2;
    const float* w2p = (s == 0) ? W2_0 : (s == 1) ? W2_1 : W2_2;
    b1cat[t] = b1p[j];
    W2cat[t] = w2p[j];
    if (t < 3) b2cat[t] = (t == 0 ? b2_0 : t == 1 ? b2_1 : b2_2)[0];
}

// ---------------- K1: fused scorer GEMM (64 rows x 768 cols) + softmax/gates + pooling ----------------
// One block per batch. Converts x fp32->bf16 during A staging; computes all 3 scorers
// (N=768), reduces to s0/s1/s2 in LDS, does the 3 softmax/gate variants, then pools
// (x rows are L2-hot from the GEMM staging reads).
__global__ __launch_bounds__(512) void scorer_pool(
        const float* __restrict__ x, const unsigned short* __restrict__ W1T,
        const float* __restrict__ b1cat, const float* __restrict__ W2cat,
        const float* __restrict__ b2cat,
        unsigned short* __restrict__ pooledcat, unsigned short* __restrict__ gx) {
    __shared__ char ldsA[64 * 128];      // 8 KB
    __shared__ char ldsB[768 * 128];     // 96 KB
    __shared__ float red[3][64][8];      // 6 KB
    __shared__ float sarr[3][64];
    __shared__ float w0s[64], w1s[64], gts[64];
    __shared__ float a0p[4][512];        // 8 KB pool partials
    int tid = threadIdx.x, lane = tid & 63, wid = tid >> 6;   // wid = col-group 0..7
    size_t b = blockIdx.x;
    size_t rowbase = b * 64;
    f32x4 acc[4][6] = {};
    for (int kt = 0; kt < 8; ++kt) {
        int k0 = kt * 64;
        __syncthreads();
        { int r = tid >> 3, ch = tid & 7;
          const float* src = x + (rowbase + r) * 512 + k0 + ch * 8;
          float4 v0 = *(const float4*)src;
          float4 v1 = *(const float4*)(src + 4);
          *(short8*)(ldsA + swz(r, ch)) = pack8(v0, v1); }
        #pragma unroll
        for (int i = 0; i < 12; ++i) {
            int idx = i * 512 + tid; int r = idx >> 3, ch = idx & 7;
            *(short8*)(ldsB + swz(r, ch)) = *(const short8*)(W1T + (size_t)r * 512 + k0 + ch * 8);
        }
        __syncthreads();
        #pragma unroll
        for (int kk = 0; kk < 2; ++kk) {
            int chunk = kk * 4 + (lane >> 4);
            short8 af[4], bfr[6];
            #pragma unroll
            for (int m = 0; m < 4; ++m)
                af[m] = *(const short8*)(ldsA + swz(m * 16 + (lane & 15), chunk));
            #pragma unroll
            for (int n = 0; n < 6; ++n)
                bfr[n] = *(const short8*)(ldsB + swz(wid * 96 + n * 16 + (lane & 15), chunk));
            #pragma unroll
            for (int m = 0; m < 4; ++m)
                #pragma unroll
                for (int n = 0; n < 6; ++n)
                    acc[m][n] = __builtin_amdgcn_mfma_f32_16x16x32_bf16(af[m], bfr[n], acc[m][n], 0, 0, 0);
        }
    }
    // epilogue: bias + GELU + W2 dot, per-scorer partials
    float b1v[6], w2v[6];
    #pragma unroll
    for (int n = 0; n < 6; ++n) {
        int col = wid * 96 + n * 16 + (lane & 15);
        b1v[n] = b1cat[col];
        w2v[n] = W2cat[col];
    }
    int lo = (wid * 96) >> 8, hi = (wid * 96 + 80) >> 8;   // wave-uniform scorer span
    #pragma unroll
    for (int m = 0; m < 4; ++m)
        #pragma unroll
        for (int j = 0; j < 4; ++j) {
            float p0 = 0.f, p1 = 0.f, p2 = 0.f;
            #pragma unroll
            for (int n = 0; n < 6; ++n) {
                float g = gelu(acc[m][n][j] + b1v[n]) * w2v[n];
                int sc = (wid * 96 + n * 16) >> 8;   // wave-uniform per n
                if (sc == 0) p0 += g; else if (sc == 1) p1 += g; else p2 += g;
            }
            if (lo <= 0 && 0 <= hi) for (int off = 1; off < 16; off <<= 1) p0 += __shfl_xor(p0, off);
            if (lo <= 1 && 1 <= hi) for (int off = 1; off < 16; off <<= 1) p1 += __shfl_xor(p1, off);
            if (lo <= 2 && 2 <= hi) for (int off = 1; off < 16; off <<= 1) p2 += __shfl_xor(p2, off);
            if ((lane & 15) == 0) {
                int row = m * 16 + (lane >> 4) * 4 + j;
                red[0][row][wid] = p0;
                red[1][row][wid] = p1;
                red[2][row][wid] = p2;
            }
        }
    __syncthreads();
    if (tid < 192) {
        int sc = tid >> 6, row = tid & 63;
        float s = b2cat[sc];
        #pragma unroll
        for (int k = 0; k < 8; ++k) s += red[sc][row][k];
        sarr[sc][row] = s;
    }
    __syncthreads();
    if (wid == 0) {
        float v = sarr[0][lane];
        float m = v;
        for (int off = 32; off; off >>= 1) m = fmaxf(m, __shfl_xor(m, off));
        float e = expf(v - m);
        float su = e;
        for (int off = 32; off; off >>= 1) su += __shfl_xor(su, off);
        w0s[lane] = e / su;
    } else if (wid == 1) {
        float v = sarr[1][lane];
        float m = v;
        for (int off = 4; off; off >>= 1) m = fmaxf(m, __shfl_xor(m, off));
        float e = expf(v - m);
        float su = e;
        for (int off = 4; off; off >>= 1) su += __shfl_xor(su, off);
        w1s[lane] = e / su;
    } else if (wid == 2) {
        gts[lane] = 1.0f / (1.0f + expf(-sarr[2][lane]));
    }
    __syncthreads();
    // pooling + gated-x: 4 cols/thread, 16 t's per t-group (vectorized loads/stores)
    {
        int c4 = (tid & 127) * 4;
        int tg = tid >> 7;               // wave-uniform (0..3)
        float a0[4] = {0.f, 0.f, 0.f, 0.f};
        float a1[4] = {0.f, 0.f, 0.f, 0.f};
        for (int t = tg * 16; t < tg * 16 + 16; ++t) {
            float4 xv = *(const float4*)(x + (rowbase + t) * 512 + c4);
            float wg0 = w0s[t], wg1 = w1s[t], gt = gts[t];
            a0[0] += wg0 * xv.x; a0[1] += wg0 * xv.y; a0[2] += wg0 * xv.z; a0[3] += wg0 * xv.w;
            a1[0] += wg1 * xv.x; a1[1] += wg1 * xv.y; a1[2] += wg1 * xv.z; a1[3] += wg1 * xv.w;
            ushort4 gv;
            gv.x = f2bf(xv.x * gt); gv.y = f2bf(xv.y * gt);
            gv.z = f2bf(xv.z * gt); gv.w = f2bf(xv.w * gt);
            *(ushort4*)(gx + (rowbase + t) * 512 + c4) = gv;
            if ((t & 7) == 7) {
                ushort4 pv;
                pv.x = f2bf(a1[0]); pv.y = f2bf(a1[1]); pv.z = f2bf(a1[2]); pv.w = f2bf(a1[3]);
                *(ushort4*)(pooledcat + (b * 8 + (t >> 3)) * 1024 + 512 + c4) = pv;
                a1[0] = a1[1] = a1[2] = a1[3] = 0.f;
            }
        }
        #pragma unroll
        for (int k = 0; k < 4; ++k) a0p[tg][c4 + k] = a0[k];
    }
    __syncthreads();
    if (tid < 128) {
        int c4 = tid * 4;
        ushort4 pv;
        float s0 = a0p[0][c4]     + a0p[1][c4]     + a0p[2][c4]     + a0p[3][c4];
        float s1 = a0p[0][c4 + 1] + a0p[1][c4 + 1] + a0p[2][c4 + 1] + a0p[3][c4 + 1];
        float s2 = a0p[0][c4 + 2] + a0p[1][c4 + 2] + a0p[2][c4 + 2] + a0p[3][c4 + 2];
        float s3 = a0p[0][c4 + 3] + a0p[1][c4 + 3] + a0p[2][c4 + 3] + a0p[3][c4 + 3];
        pv.x = f2bf(s0); pv.y = f2bf(s1); pv.z = f2bf(s2); pv.w = f2bf(s3);
        #pragma unroll
        for (int g = 0; g < 8; ++g)
            *(ushort4*)(pooledcat + (b * 8 + g) * 1024 + c4) = pv;
    }
}

// ---------------- K3: base GEMM [8192,1024]@[1024,512] + bp ----------------
__global__ __launch_bounds__(256) void base_gemm(
        const unsigned short* __restrict__ pooledcat, const unsigned short* __restrict__ WpT,
        const float* __restrict__ bp, float* __restrict__ baseout) {
    __shared__ char ldsA[32 * 128];
    __shared__ char ldsB[512 * 128];
    int tid = threadIdx.x, lane = tid & 63, w = tid >> 6;   // 4 waves: cols w*128, rows 0..31
    size_t rowbase = (size_t)blockIdx.x * 32;
    f32x4 acc[2][8] = {};
    for (int kt = 0; kt < 16; ++kt) {
        int k0 = kt * 64;
        __syncthreads();
        { int r = tid >> 3, ch = tid & 7;
          *(int4*)(ldsA + swz(r, ch)) = *(const int4*)(pooledcat + (rowbase + r) * 1024 + k0 + ch * 8); }
        for (int i = 0; i < 16; ++i) {
            int idx = i * 256 + tid; int r = idx >> 3, ch = idx & 7;
            *(int4*)(ldsB + swz(r, ch)) = *(const int4*)(WpT + (size_t)r * 1536 + k0 + ch * 8);
        }
        __syncthreads();
        for (int kk = 0; kk < 2; ++kk) {
            int chunk = kk * 4 + (lane >> 4);
            short8 af[2], bfr[8];
            #pragma unroll
            for (int m = 0; m < 2; ++m)
                af[m] = *(const short8*)(ldsA + swz(m * 16 + (lane & 15), chunk));
            #pragma unroll
            for (int n = 0; n < 8; ++n)
                bfr[n] = *(const short8*)(ldsB + swz(w * 128 + n * 16 + (lane & 15), chunk));
            #pragma unroll
            for (int m = 0; m < 2; ++m)
                #pragma unroll
                for (int n = 0; n < 8; ++n)
                    acc[m][n] = __builtin_amdgcn_mfma_f32_16x16x32_bf16(af[m], bfr[n], acc[m][n], 0, 0, 0);
        }
    }
    #pragma unroll
    for (int n = 0; n < 8; ++n) {
        int col = w * 128 + n * 16 + (lane & 15);
        float bpv = bp[col];
        #pragma unroll
        for (int m = 0; m < 2; ++m)
            #pragma unroll
            for (int j = 0; j < 4; ++j) {
                int row = m * 16 + (lane >> 4) * 4 + j;
                baseout[(rowbase + row) * 512 + col] = acc[m][n][j] + bpv;
            }
    }
}

// ---------------- K4: final GEMM (gated x @ Wp2) + base + GELU + LayerNorm ----------------
// BM=128 (2 batches/block), 8 waves, wave tile 64x128 (acc[4][8]).
__global__ __launch_bounds__(512) void final_gemm_ln(
        const unsigned short* __restrict__ gx, const unsigned short* __restrict__ WpT,
        const float* __restrict__ base, const float* __restrict__ ln_g,
        const float* __restrict__ ln_b, float* __restrict__ out) {
    __shared__ char ldsA[128 * 128];   // 16 KB
    __shared__ char ldsB[512 * 128];   // 64 KB
    __shared__ float redS[128][4], redQ[128][4], muL[128], rsL[128];
    int tid = threadIdx.x, lane = tid & 63, w = tid >> 6;
    int wr = w >> 2, wc = w & 3;         // wr: 64-row half (==batch), wc: 128-col quarter
    size_t rowbase = (size_t)blockIdx.x * 128;
    size_t b2base = (size_t)blockIdx.x * 2;
    f32x4 acc[4][8] = {};
    for (int kt = 0; kt < 8; ++kt) {
        int k0 = kt * 64;
        __syncthreads();
        #pragma unroll
        for (int i = 0; i < 2; ++i) {
            int idx = i * 512 + tid; int r = idx >> 3, ch = idx & 7;
            *(int4*)(ldsA + swz(r, ch)) = *(const int4*)(gx + (rowbase + r) * 512 + k0 + ch * 8);
        }
        #pragma unroll
        for (int i = 0; i < 8; ++i) {
            int idx = i * 512 + tid; int r = idx >> 3, ch = idx & 7;
            *(int4*)(ldsB + swz(r, ch)) = *(const int4*)(WpT + (size_t)r * 1536 + 1024 + k0 + ch * 8);
        }
        __syncthreads();
        #pragma unroll
        for (int kk = 0; kk < 2; ++kk) {
            int chunk = kk * 4 + (lane >> 4);
            short8 af[4], bfr[8];
            #pragma unroll
            for (int m = 0; m < 4; ++m)
                af[m] = *(const short8*)(ldsA + swz(wr * 64 + m * 16 + (lane & 15), chunk));
            #pragma unroll
            for (int n = 0; n < 8; ++n)
                bfr[n] = *(const short8*)(ldsB + swz(wc * 128 + n * 16 + (lane & 15), chunk));
            #pragma unroll
            for (int m = 0; m < 4; ++m)
                #pragma unroll
                for (int n = 0; n < 8; ++n)
                    acc[m][n] = __builtin_amdgcn_mfma_f32_16x16x32_bf16(af[m], bfr[n], acc[m][n], 0, 0, 0);
        }
    }
    // epilogue: + base, GELU, LayerNorm
    float lngv[8], lnbv[8];
    int cols[8];
    #pragma unroll
    for (int n = 0; n < 8; ++n) {
        int col = wc * 128 + n * 16 + (lane & 15);
        cols[n] = col;
        lngv[n] = ln_g[col];
        lnbv[n] = ln_b[col];
    }
    #pragma unroll
    for (int m = 0; m < 4; ++m) {
        int gi = m * 2 + ((lane >> 4) >> 1);   // (row&63)>>3, j-independent
        #pragma unroll
        for (int n = 0; n < 8; ++n) {
            float bv = base[((b2base + wr) * 8 + gi) * 512 + cols[n]];
            #pragma unroll
            for (int j = 0; j < 4; ++j)
                acc[m][n][j] = gelu(acc[m][n][j] + bv);
        }
    }
    #pragma unroll
    for (int m = 0; m < 4; ++m)
        #pragma unroll
        for (int j = 0; j < 4; ++j) {
            float s = 0.f, q = 0.f;
            #pragma unroll
            for (int n = 0; n < 8; ++n) { float v = acc[m][n][j]; s += v; q += v * v; }
            for (int off = 1; off < 16; off <<= 1) { s += __shfl_xor(s, off); q += __shfl_xor(q, off); }
            if ((lane & 15) == 0) {
                int row = wr * 64 + m * 16 + (lane >> 4) * 4 + j;
                redS[row][wc] = s;
                redQ[row][wc] = q;
            }
        }
    __syncthreads();
    if (tid < 128) {
        float s = redS[tid][0] + redS[tid][1] + redS[tid][2] + redS[tid][3];
        float q = redQ[tid][0] + redQ[tid][1] + redQ[tid][2] + redQ[tid][3];
        float mu = s * (1.0f / 512.0f);
        float var = q * (1.0f / 512.0f) - mu * mu;
        muL[tid] = mu;
        rsL[tid] = rsqrtf(var + 1e-5f);
    }
    __syncthreads();
    #pragma unroll
    for (int m = 0; m < 4; ++m)
        #pragma unroll
        for (int j = 0; j < 4; ++j) {
            int row = wr * 64 + m * 16 + (lane >> 4) * 4 + j;
            float mu = muL[row], rs = rsL[row];
            #pragma unroll
            for (int n = 0; n < 8; ++n)
                out[(rowbase + row) * 512 + cols[n]] = (acc[m][n][j] - mu) * rs * lngv[n] + lnbv[n];
        }
}

extern "C" void kernel_launch(void* const* d_in, const int* in_sizes, int n_in,
                              void* d_out, int out_size, void* d_ws, size_t ws_size,
                              hipStream_t stream) {
    const float* x    = (const float*)d_in[0];
    const float* W1a[3] = { (const float*)d_in[1], (const float*)d_in[5], (const float*)d_in[9] };
    const float* b1a[3] = { (const float*)d_in[2], (const float*)d_in[6], (const float*)d_in[10] };
    const float* W2a[3] = { (const float*)d_in[3], (const float*)d_in[7], (const float*)d_in[11] };
    const float* b2a[3] = { (const float*)d_in[4], (const float*)d_in[8], (const float*)d_in[12] };
    const float* Wp   = (const float*)d_in[13];
    const float* bp   = (const float*)d_in[14];
    const float* ln_g = (const float*)d_in[15];
    const float* ln_b = (const float*)d_in[16];
    float* out = (float*)d_out;

    char* ws = (char*)d_ws;
    size_t off = 0;
    auto carve = [&](size_t bytes) { char* p = ws + off; off += (bytes + 255) & ~(size_t)255; return p; };
    unsigned short* gx        = (unsigned short*)carve((size_t)BT * D * 2);        // 67.1 MB
    unsigned short* W1T       = (unsigned short*)carve((size_t)NH * D * 2);        // 786 KB
    unsigned short* WpT       = (unsigned short*)carve((size_t)D * 1536 * 2);      // 1.57 MB
    float*          b1cat     = (float*)carve(NH * 4);
    float*          W2cat     = (float*)carve(NH * 4);
    float*          b2cat     = (float*)carve(16);
    unsigned short* pooledcat = (unsigned short*)carve((size_t)NB * 8 * 1024 * 2); // 16.8 MB
    float*          base      = (float*)carve((size_t)NB * 8 * 512 * 4);           // 16.8 MB

    // 1. weight prep
    dim3 tb(32, 8);
    for (int s = 0; s < 3; ++s)
        transpose_to_bf16<<<dim3(16, 8), tb, 0, stream>>>(W1a[s], W1T + (size_t)s * 256 * 512, 512, 256, 512);
    transpose_to_bf16<<<dim3(48, 16), tb, 0, stream>>>(Wp, WpT, 1536, 512, 1536);
    prep_cat<<<1, 768, 0, stream>>>(b1a[0], b1a[1], b1a[2], W2a[0], W2a[1], W2a[2],
                                    b2a[0], b2a[1], b2a[2], b1cat, W2cat, b2cat);
    // 2. fused scorers + softmax/gates + pooling (writes pooledcat, gx)
    scorer_pool<<<1024, 512, 0, stream>>>(x, W1T, b1cat, W2cat, b2cat, pooledcat, gx);
    // 3. base = pooledcat @ Wp[0:1024] + bp
    base_gemm<<<256, 256, 0, stream>>>(pooledcat, WpT, bp, base);
    // 4. final = LN(GELU(base + gx @ Wp[1024:1536]))
    final_gemm_ln<<<512, 512, 0, stream>>>(gx, WpT, base, ln_g, ln_b, out);
}